// Round 4
// baseline (57.373 us; speedup 1.0000x reference)
//
#include <hip/hip_runtime.h>
#include <hip/hip_bf16.h>

// ContrastiveLoss fused kernel for MI355X (gfx950).
//
// Math reduction (T=0.5):
//   f = x / max(||x||, 1e-8)   (rows)
//   s_ij = f_i . f_j
//   den_i = sum_{j: label_j != label_i} exp(2 s_ij)
//   loss  = sum_i [ c_i * log(den_i) - sum_{j same label, j != i} 2 s_ij ]
//           / (sum_i c_i + 1e-5),   c_i = count(label_i) - 1
//
// N=4096, D=512, labels in [0,100).
//
// Round 4: k2 B-tiles staged FRAGMENT-MAJOR in LDS: chunk (js,kt) is a
// contiguous 1 KB block holding the wave's MFMA B-operand, read back at
// base + lane*16 (conflict-free linear; kt becomes a ds_read offset
// immediate). Round-3 row-major+XOR layout was an 8-way bank conflict
// (bank slot = bits 4-6 of col only -> 8 lanes/slot) = 2.94x LDS cost.

typedef short short8 __attribute__((ext_vector_type(8)));
typedef float floatx4 __attribute__((ext_vector_type(4)));
typedef unsigned short u16;
typedef unsigned int u32;

#define N_ROWS 4096
#define DIM 512
#define ROWB 1024              // bytes per row
#define EPS_NORM 1e-8f
#define EPS_DEN 1e-5f
#define BI 128                 // i-rows per block (4 waves x 32)
#define NBLK_I (N_ROWS / BI)   // 32
#define JSPAN 128              // j-cols per block
#define NJT (JSPAN / 32)       // 4 slabs of 32

static __device__ inline u16 f32_to_bf16(float f) {
  u32 u = __float_as_uint(f);
  u32 r = (u + 0x7FFFu + ((u >> 16) & 1u)) >> 16;   // RNE
  return (u16)r;
}

static __device__ inline void load_lds16(const char* g, char* l) {
  __builtin_amdgcn_global_load_lds(
      (const __attribute__((address_space(1))) void*)g,
      (__attribute__((address_space(3))) void*)l, 16, 0, 0);
}

// wave-per-row normalize + bf16 pack; grid 1024 x 256
__global__ void k1_normalize(const float* __restrict__ x,
                             u16* __restrict__ fb,
                             float* __restrict__ den, float* __restrict__ pos) {
  const int row = blockIdx.x * 4 + (threadIdx.x >> 6);
  const int lane = threadIdx.x & 63;
  const float4* src = reinterpret_cast<const float4*>(x + (size_t)row * DIM);
  float4 v0 = src[lane * 2];
  float4 v1 = src[lane * 2 + 1];
  float ss = v0.x*v0.x + v0.y*v0.y + v0.z*v0.z + v0.w*v0.w
           + v1.x*v1.x + v1.y*v1.y + v1.z*v1.z + v1.w*v1.w;
#pragma unroll
  for (int m = 1; m < 64; m <<= 1) ss += __shfl_xor(ss, m, 64);
  float scale = 1.f / fmaxf(sqrtf(ss), EPS_NORM);
  uint4 o;
  o.x = ((u32)f32_to_bf16(v0.y * scale) << 16) | (u32)f32_to_bf16(v0.x * scale);
  o.y = ((u32)f32_to_bf16(v0.w * scale) << 16) | (u32)f32_to_bf16(v0.z * scale);
  o.z = ((u32)f32_to_bf16(v1.y * scale) << 16) | (u32)f32_to_bf16(v1.x * scale);
  o.w = ((u32)f32_to_bf16(v1.w * scale) << 16) | (u32)f32_to_bf16(v1.z * scale);
  reinterpret_cast<uint4*>(fb + (size_t)row * DIM)[lane] = o;
  if (lane == 0) { den[row] = 0.f; pos[row] = 0.f; }
}

// fused sim-GEMM + per-row reduction.
__global__ __launch_bounds__(256, 2) void k2_fused(
    const u16* __restrict__ fb, const int* __restrict__ labels,
    float* __restrict__ den, float* __restrict__ pos) {
  // fragment-major B: 2 buffers x 32 chunks (js*16+kt) x 1 KB
  __shared__ u16 Bsh[2 * 32 * 512];
  __shared__ int labj_sh[JSPAN];

  const char* fbb = (const char*)fb;
  char* bshb = (char*)Bsh;

  const int bid = blockIdx.x;
  const int itile = bid & (NBLK_I - 1);
  const int jch = bid >> 5;               // 32 j-chunks
  const int tid = threadIdx.x;
  const int wv = tid >> 6;
  const int lane = tid & 63;
  const int l15 = lane & 15;
  const int kg = lane >> 4;               // 0..3

  const int ib = itile * BI;
  const int jbase = jch * JSPAN;

  // stage one 32-row B slab as 32 fragment chunks; wave wv stages chunks
  // wv*8 .. wv*8+7.  chunk c = js*16 + kt holds, at byte lane*16, the
  // bytes fb[grow + js*16 + (lane&15)][k bytes kt*64 + (lane>>4)*16 .. +16)
  // -> LDS dest is wave-uniform base + lane*16 (global_load_lds constraint),
  //    the per-lane gather happens on the GLOBAL source side.
#define STAGE(bufsel, grow) do {                                            \
    _Pragma("unroll")                                                       \
    for (int i_ = 0; i_ < 8; ++i_) {                                        \
      const int c_ = wv * 8 + i_;                                           \
      const int js_ = c_ >> 4;                                              \
      const int kt_ = c_ & 15;                                              \
      load_lds16(fbb + (size_t)((grow) + js_ * 16 + l15) * ROWB             \
                     + kt_ * 64 + kg * 16,                                  \
                 bshb + (bufsel) * 32768 + c_ * 1024 + lane * 16);          \
    }                                                                       \
  } while (0)

  // prologue: stage slab 0 into buf 0, labels into LDS
  STAGE(0, jbase);
  if (tid < JSPAN) labj_sh[tid] = labels[jbase + tid];

  // A fragments: 32 rows/wave (2 sets of 16), K=512, register-resident.
  // lane (kg,l15) holds A[row = set_base + l15][k = kt*32 + kg*8 + e]
  short8 a[2][16];
#pragma unroll
  for (int s = 0; s < 2; ++s) {
    const char* arow = fbb + (size_t)(ib + wv * 32 + s * 16 + l15) * ROWB + kg * 16;
#pragma unroll
    for (int kt = 0; kt < 16; ++kt)
      a[s][kt] = *reinterpret_cast<const short8*>(arow + kt * 64);
  }
  // pin A in VGPRs (round-1 pathology: compiler sank loads into the loop)
#pragma unroll
  for (int s = 0; s < 2; ++s)
#pragma unroll
    for (int kt = 0; kt < 16; ++kt)
      asm volatile("" : "+v"(a[s][kt]));

  // C/D layout (verified gfx950): col = lane&15 (j), row = kg*4 + r (i)
  int i_idx[2][4]; int labi[2][4];
#pragma unroll
  for (int s = 0; s < 2; ++s)
#pragma unroll
    for (int r = 0; r < 4; ++r) {
      i_idx[s][r] = ib + wv * 32 + s * 16 + kg * 4 + r;
      labi[s][r] = labels[i_idx[s][r]];
    }

  float den_acc[2][4] = {{0.f,0.f,0.f,0.f},{0.f,0.f,0.f,0.f}};
  float pos_acc[2][4] = {{0.f,0.f,0.f,0.f},{0.f,0.f,0.f,0.f}};

  __syncthreads();   // buf0 staged, labels ready

  for (int jt = 0; jt < NJT; ++jt) {
    const int cur = jt & 1;
    if (jt + 1 < NJT) STAGE(cur ^ 1, jbase + (jt + 1) * 32);

    const int j0 = jt * 32;
    const int jrow0 = jbase + j0 + l15;        // js = 0
    const int jrow1 = jrow0 + 16;              // js = 1
    const int labj0 = labj_sh[j0 + l15];
    const int labj1 = labj_sh[j0 + 16 + l15];

    // 4 independent MFMA chains: (i-set 0/1) x (j-subtile 0/1).
    // B reads are linear (base + lane*16 + kt*1024 immediate): conflict-free.
    floatx4 acc00 = {0.f,0.f,0.f,0.f}, acc01 = {0.f,0.f,0.f,0.f};
    floatx4 acc10 = {0.f,0.f,0.f,0.f}, acc11 = {0.f,0.f,0.f,0.f};
    const char* bbase = bshb + cur * 32768 + lane * 16;
#pragma unroll
    for (int kt = 0; kt < 16; ++kt) {
      short8 b0 = *reinterpret_cast<const short8*>(bbase + kt * 1024);
      short8 b1 = *reinterpret_cast<const short8*>(bbase + 16384 + kt * 1024);
      acc00 = __builtin_amdgcn_mfma_f32_16x16x32_bf16(a[0][kt], b0, acc00, 0, 0, 0);
      acc10 = __builtin_amdgcn_mfma_f32_16x16x32_bf16(a[1][kt], b0, acc10, 0, 0, 0);
      acc01 = __builtin_amdgcn_mfma_f32_16x16x32_bf16(a[0][kt], b1, acc01, 0, 0, 0);
      acc11 = __builtin_amdgcn_mfma_f32_16x16x32_bf16(a[1][kt], b1, acc11, 0, 0, 0);
    }

#pragma unroll
    for (int s = 0; s < 2; ++s) {
      floatx4 aj0 = s ? acc10 : acc00;
      floatx4 aj1 = s ? acc11 : acc01;
#pragma unroll
      for (int r = 0; r < 4; ++r) {
        float s20 = 2.f * aj0[r];
        float s21 = 2.f * aj1[r];
        float e0 = __expf(s20);
        float e1 = __expf(s21);
        bool sm0 = (labj0 == labi[s][r]);
        bool sm1 = (labj1 == labi[s][r]);
        den_acc[s][r] += (sm0 ? 0.f : e0) + (sm1 ? 0.f : e1);
        float p = 0.f;
        if (sm0 && (jrow0 != i_idx[s][r])) p += s20;
        if (sm1 && (jrow1 != i_idx[s][r])) p += s21;
        pos_acc[s][r] += p;
      }
    }
    __syncthreads();   // staging for jt+1 done; safe to flip buffers
  }

  // reduce across the 16 cols (lanes with same kg), one atomic per row
#pragma unroll
  for (int s = 0; s < 2; ++s)
#pragma unroll
    for (int r = 0; r < 4; ++r) {
      float d = den_acc[s][r], p = pos_acc[s][r];
#pragma unroll
      for (int m = 1; m < 16; m <<= 1) {
        d += __shfl_xor(d, m, 64);
        p += __shfl_xor(p, m, 64);
      }
      if (l15 == 0) {
        atomicAdd(&den[i_idx[s][r]], d);
        atomicAdd(&pos[i_idx[s][r]], p);
      }
    }
#undef STAGE
}

__global__ void k3_final(const float* __restrict__ den, const float* __restrict__ pos,
                         const int* __restrict__ labels, float* __restrict__ out) {
  const int tid = threadIdx.x;   // 256 threads, 1 block
  __shared__ int hist[128];
  __shared__ float sn[4], sz[4];
  if (tid < 128) hist[tid] = 0;
  __syncthreads();
  for (int i = tid; i < N_ROWS; i += 256) atomicAdd(&hist[labels[i]], 1);
  __syncthreads();

  float num = 0.f, nnz = 0.f;
  for (int i = tid; i < N_ROWS; i += 256) {
    int c = hist[labels[i]] - 1;
    num += (float)c * logf(den[i]) - pos[i];
    nnz += (float)c;
  }
#pragma unroll
  for (int m = 1; m < 64; m <<= 1) {
    num += __shfl_xor(num, m, 64);
    nnz += __shfl_xor(nnz, m, 64);
  }
  if ((tid & 63) == 0) { sn[tid >> 6] = num; sz[tid >> 6] = nnz; }
  __syncthreads();
  if (tid == 0) {
    float tn = sn[0] + sn[1] + sn[2] + sn[3];
    float tz = sz[0] + sz[1] + sz[2] + sz[3];
    out[0] = tn / (tz + EPS_DEN);
  }
}

extern "C" void kernel_launch(void* const* d_in, const int* in_sizes, int n_in,
                              void* d_out, int out_size, void* d_ws, size_t ws_size,
                              hipStream_t stream) {
  const float* x = (const float*)d_in[0];
  const int* labels = (const int*)d_in[1];

  // ws layout: fb (bf16 4096x512 = 4MB) | den f32[4096] | pos f32[4096]
  u16* fb = (u16*)d_ws;
  float* den = (float*)((char*)d_ws + (size_t)N_ROWS * DIM * 2);
  float* pos = den + N_ROWS;
  float* out = (float*)d_out;

  hipLaunchKernelGGL(k1_normalize, dim3(N_ROWS / 4), dim3(256), 0, stream,
                     x, fb, den, pos);
  hipLaunchKernelGGL(k2_fused, dim3(NBLK_I * (N_ROWS / JSPAN)), dim3(256), 0, stream,
                     fb, labels, den, pos);
  hipLaunchKernelGGL(k3_final, dim3(1), dim3(256), 0, stream,
                     den, pos, labels, out);
}

// Round 5
// 42.905 us; speedup vs baseline: 1.3372x; 1.3372x over previous
//
#include <hip/hip_runtime.h>
#include <hip/hip_bf16.h>

// ContrastiveLoss fused kernel for MI355X (gfx950).
//
// Math reduction (T=0.5):
//   f = x / max(||x||, 1e-8)   (rows)
//   s_ij = f_i . f_j
//   den_i = sum_{j: label_j != label_i} exp(2 s_ij)
//   loss  = sum_i [ c_i * log(den_i) - sum_{j same label, j != i} 2 s_ij ]
//           / (sum_i c_i + 1e-5),   c_i = count(label_i) - 1
//
// N=4096, D=512, labels in [0,100).
//
// Round 5: normalized bf16 matrix is stored FRAGMENT-MAJOR in global
// memory (G[g][kt][lane*16], g = 16-row group, kt = 32-elem k-chunk,
// lane = kg*16 + row-in-group). Both MFMA A- and B-fragments use the
// identical lane->(row,k) map, so every k2 global access (A prologue
// loads AND global_load_lds staging) is one contiguous 1 KB segment.
// Round-4 pathology: row-major fb made every wave global op a 16-way
// 64B scatter -> per-jt vmcnt(0) barrier drain ~2k cyc (k2 stuck at
// 41 us, all pipes <20%).

typedef short short8 __attribute__((ext_vector_type(8)));
typedef float floatx4 __attribute__((ext_vector_type(4)));
typedef unsigned short u16;
typedef unsigned int u32;

#define N_ROWS 4096
#define DIM 512
#define GRPB 16384             // bytes per 16-row fragment group (16*1024)
#define EPS_NORM 1e-8f
#define EPS_DEN 1e-5f
#define BI 128                 // i-rows per block (4 waves x 32)
#define NBLK_I (N_ROWS / BI)   // 32
#define JSPAN 128              // j-cols per block
#define NJT (JSPAN / 32)       // 4 slabs of 32

static __device__ inline u16 f32_to_bf16(float f) {
  u32 u = __float_as_uint(f);
  u32 r = (u + 0x7FFFu + ((u >> 16) & 1u)) >> 16;   // RNE
  return (u16)r;
}

static __device__ inline void load_lds16(const char* g, char* l) {
  __builtin_amdgcn_global_load_lds(
      (const __attribute__((address_space(1))) void*)g,
      (__attribute__((address_space(3))) void*)l, 16, 0, 0);
}

// wave-per-row normalize + bf16 pack, fragment-major store; grid 1024 x 256.
// lane owns row elements k = lane*8 .. lane*8+7  ->  kt = lane>>2, kg = lane&3,
// chunk byte = (kg*16 + (row&15))*16.
__global__ void k1_normalize(const float* __restrict__ x,
                             u16* __restrict__ G,
                             float* __restrict__ den, float* __restrict__ pos) {
  const int row = blockIdx.x * 4 + (threadIdx.x >> 6);
  const int lane = threadIdx.x & 63;
  const float4* src = reinterpret_cast<const float4*>(x + (size_t)row * DIM);
  float4 v0 = src[lane * 2];
  float4 v1 = src[lane * 2 + 1];
  float ss = v0.x*v0.x + v0.y*v0.y + v0.z*v0.z + v0.w*v0.w
           + v1.x*v1.x + v1.y*v1.y + v1.z*v1.z + v1.w*v1.w;
#pragma unroll
  for (int m = 1; m < 64; m <<= 1) ss += __shfl_xor(ss, m, 64);
  float scale = 1.f / fmaxf(sqrtf(ss), EPS_NORM);
  uint4 o;
  o.x = ((u32)f32_to_bf16(v0.y * scale) << 16) | (u32)f32_to_bf16(v0.x * scale);
  o.y = ((u32)f32_to_bf16(v0.w * scale) << 16) | (u32)f32_to_bf16(v0.z * scale);
  o.z = ((u32)f32_to_bf16(v1.y * scale) << 16) | (u32)f32_to_bf16(v1.x * scale);
  o.w = ((u32)f32_to_bf16(v1.w * scale) << 16) | (u32)f32_to_bf16(v1.z * scale);
  char* dst = (char*)G + (size_t)(row >> 4) * GRPB + (lane >> 2) * 1024
            + ((lane & 3) * 16 + (row & 15)) * 16;
  *reinterpret_cast<uint4*>(dst) = o;
  if (lane == 0) { den[row] = 0.f; pos[row] = 0.f; }
}

// fused sim-GEMM + per-row reduction.
__global__ __launch_bounds__(256, 2) void k2_fused(
    const u16* __restrict__ G, const int* __restrict__ labels,
    float* __restrict__ den, float* __restrict__ pos) {
  // fragment-major B: 2 buffers x 32 chunks (js*16+kt) x 1 KB
  __shared__ u16 Bsh[2 * 32 * 512];
  __shared__ int labj_sh[JSPAN];

  const char* Gb = (const char*)G;
  char* bshb = (char*)Bsh;

  const int bid = blockIdx.x;
  const int itile = bid & (NBLK_I - 1);
  const int jch = bid >> 5;               // 32 j-chunks
  const int tid = threadIdx.x;
  const int wv = tid >> 6;
  const int lane = tid & 63;
  const int l15 = lane & 15;
  const int kg = lane >> 4;               // 0..3

  const int ib = itile * BI;
  const int jbase = jch * JSPAN;

  // stage one 32-row B slab (2 fragment groups) as 32 chunks; wave wv stages
  // chunks wv*8 .. wv*8+7. Source AND dest are contiguous 1 KB (lane*16).
#define STAGE(bufsel, grow) do {                                            \
    _Pragma("unroll")                                                       \
    for (int i_ = 0; i_ < 8; ++i_) {                                        \
      const int c_ = wv * 8 + i_;                                           \
      load_lds16(Gb + (size_t)(((grow) >> 4) + (c_ >> 4)) * GRPB            \
                    + (c_ & 15) * 1024 + lane * 16,                         \
                 bshb + (bufsel) * 32768 + c_ * 1024 + lane * 16);          \
    }                                                                       \
  } while (0)

  // prologue: stage slab 0 into buf 0, labels into LDS
  STAGE(0, jbase);
  if (tid < JSPAN) labj_sh[tid] = labels[jbase + tid];

  // A fragments: 32 rows/wave = 2 fragment groups, K=512, register-resident.
  // group g holds exactly the wave's 16-row A-fragment set; load is
  // contiguous 1 KB per kt.
  short8 a[2][16];
#pragma unroll
  for (int s = 0; s < 2; ++s) {
    const char* abase = Gb + (size_t)((ib >> 4) + wv * 2 + s) * GRPB + lane * 16;
#pragma unroll
    for (int kt = 0; kt < 16; ++kt)
      a[s][kt] = *reinterpret_cast<const short8*>(abase + kt * 1024);
  }
  // pin A in VGPRs (round-1 pathology: compiler sank loads into the loop)
#pragma unroll
  for (int s = 0; s < 2; ++s)
#pragma unroll
    for (int kt = 0; kt < 16; ++kt)
      asm volatile("" : "+v"(a[s][kt]));

  // C/D layout (verified gfx950): col = lane&15 (j), row = kg*4 + r (i)
  int i_idx[2][4]; int labi[2][4];
#pragma unroll
  for (int s = 0; s < 2; ++s)
#pragma unroll
    for (int r = 0; r < 4; ++r) {
      i_idx[s][r] = ib + wv * 32 + s * 16 + kg * 4 + r;
      labi[s][r] = labels[i_idx[s][r]];
    }

  float den_acc[2][4] = {{0.f,0.f,0.f,0.f},{0.f,0.f,0.f,0.f}};
  float pos_acc[2][4] = {{0.f,0.f,0.f,0.f},{0.f,0.f,0.f,0.f}};

  __syncthreads();   // buf0 staged, labels ready

  for (int jt = 0; jt < NJT; ++jt) {
    const int cur = jt & 1;
    if (jt + 1 < NJT) STAGE(cur ^ 1, jbase + (jt + 1) * 32);

    const int j0 = jt * 32;
    const int jrow0 = jbase + j0 + l15;        // js = 0
    const int jrow1 = jrow0 + 16;              // js = 1
    const int labj0 = labj_sh[j0 + l15];
    const int labj1 = labj_sh[j0 + 16 + l15];

    // 4 independent MFMA chains: (i-set 0/1) x (j-subtile 0/1).
    // B reads are linear (base + lane*16 + kt*1024 immediate): conflict-free.
    floatx4 acc00 = {0.f,0.f,0.f,0.f}, acc01 = {0.f,0.f,0.f,0.f};
    floatx4 acc10 = {0.f,0.f,0.f,0.f}, acc11 = {0.f,0.f,0.f,0.f};
    const char* bbase = bshb + cur * 32768 + lane * 16;
#pragma unroll
    for (int kt = 0; kt < 16; ++kt) {
      short8 b0 = *reinterpret_cast<const short8*>(bbase + kt * 1024);
      short8 b1 = *reinterpret_cast<const short8*>(bbase + 16384 + kt * 1024);
      acc00 = __builtin_amdgcn_mfma_f32_16x16x32_bf16(a[0][kt], b0, acc00, 0, 0, 0);
      acc10 = __builtin_amdgcn_mfma_f32_16x16x32_bf16(a[1][kt], b0, acc10, 0, 0, 0);
      acc01 = __builtin_amdgcn_mfma_f32_16x16x32_bf16(a[0][kt], b1, acc01, 0, 0, 0);
      acc11 = __builtin_amdgcn_mfma_f32_16x16x32_bf16(a[1][kt], b1, acc11, 0, 0, 0);
    }

#pragma unroll
    for (int s = 0; s < 2; ++s) {
      floatx4 aj0 = s ? acc10 : acc00;
      floatx4 aj1 = s ? acc11 : acc01;
#pragma unroll
      for (int r = 0; r < 4; ++r) {
        float s20 = 2.f * aj0[r];
        float s21 = 2.f * aj1[r];
        float e0 = __expf(s20);
        float e1 = __expf(s21);
        bool sm0 = (labj0 == labi[s][r]);
        bool sm1 = (labj1 == labi[s][r]);
        den_acc[s][r] += (sm0 ? 0.f : e0) + (sm1 ? 0.f : e1);
        float p = 0.f;
        if (sm0 && (jrow0 != i_idx[s][r])) p += s20;
        if (sm1 && (jrow1 != i_idx[s][r])) p += s21;
        pos_acc[s][r] += p;
      }
    }
    __syncthreads();   // staging for jt+1 done; safe to flip buffers
  }

  // reduce across the 16 cols (lanes with same kg), one atomic per row
#pragma unroll
  for (int s = 0; s < 2; ++s)
#pragma unroll
    for (int r = 0; r < 4; ++r) {
      float d = den_acc[s][r], p = pos_acc[s][r];
#pragma unroll
      for (int m = 1; m < 16; m <<= 1) {
        d += __shfl_xor(d, m, 64);
        p += __shfl_xor(p, m, 64);
      }
      if (l15 == 0) {
        atomicAdd(&den[i_idx[s][r]], d);
        atomicAdd(&pos[i_idx[s][r]], p);
      }
    }
#undef STAGE
}

__global__ void k3_final(const float* __restrict__ den, const float* __restrict__ pos,
                         const int* __restrict__ labels, float* __restrict__ out) {
  const int tid = threadIdx.x;   // 256 threads, 1 block
  __shared__ int hist[128];
  __shared__ float sn[4], sz[4];
  if (tid < 128) hist[tid] = 0;
  __syncthreads();
  for (int i = tid; i < N_ROWS; i += 256) atomicAdd(&hist[labels[i]], 1);
  __syncthreads();

  float num = 0.f, nnz = 0.f;
  for (int i = tid; i < N_ROWS; i += 256) {
    int c = hist[labels[i]] - 1;
    num += (float)c * logf(den[i]) - pos[i];
    nnz += (float)c;
  }
#pragma unroll
  for (int m = 1; m < 64; m <<= 1) {
    num += __shfl_xor(num, m, 64);
    nnz += __shfl_xor(nnz, m, 64);
  }
  if ((tid & 63) == 0) { sn[tid >> 6] = num; sz[tid >> 6] = nnz; }
  __syncthreads();
  if (tid == 0) {
    float tn = sn[0] + sn[1] + sn[2] + sn[3];
    float tz = sz[0] + sz[1] + sz[2] + sz[3];
    out[0] = tn / (tz + EPS_DEN);
  }
}

extern "C" void kernel_launch(void* const* d_in, const int* in_sizes, int n_in,
                              void* d_out, int out_size, void* d_ws, size_t ws_size,
                              hipStream_t stream) {
  const float* x = (const float*)d_in[0];
  const int* labels = (const int*)d_in[1];

  // ws layout: G (bf16 fragment-major, 4MB) | den f32[4096] | pos f32[4096]
  u16* G = (u16*)d_ws;
  float* den = (float*)((char*)d_ws + (size_t)N_ROWS * DIM * 2);
  float* pos = den + N_ROWS;
  float* out = (float*)d_out;

  hipLaunchKernelGGL(k1_normalize, dim3(N_ROWS / 4), dim3(256), 0, stream,
                     x, G, den, pos);
  hipLaunchKernelGGL(k2_fused, dim3(NBLK_I * (N_ROWS / JSPAN)), dim3(256), 0, stream,
                     G, labels, den, pos);
  hipLaunchKernelGGL(k3_final, dim3(1), dim3(256), 0, stream,
                     den, pos, labels, out);
}